// Round 4
// baseline (1497.414 us; speedup 1.0000x reference)
//
#include <hip/hip_runtime.h>

#define TT 256
#define VV 95

__device__ __forceinline__ float fast_sigmoid(float v) {
    return __builtin_amdgcn_rcpf(1.0f + __expf(-v));
}
__device__ __forceinline__ float fast_tanh(float v) {
    return 1.0f - 2.0f * __builtin_amdgcn_rcpf(__expf(2.0f * v) + 1.0f);
}
// LDS-only block sync: lgkmcnt drain + raw barrier. Avoids __syncthreads()'s
// workgroup release fence, which drains vmcnt(0) and would serialize the
// in-flight global prefetch every step.
__device__ __forceinline__ void block_sync_lds() {
    asm volatile("s_waitcnt lgkmcnt(0)" ::: "memory");
    __builtin_amdgcn_s_barrier();
}

__device__ __forceinline__ float dot16(const float* w, float4 a, float4 b, float4 c, float4 d) {
    float s = 0.0f;
    s = fmaf(w[0],  a.x, s); s = fmaf(w[1],  a.y, s); s = fmaf(w[2],  a.z, s); s = fmaf(w[3],  a.w, s);
    s = fmaf(w[4],  b.x, s); s = fmaf(w[5],  b.y, s); s = fmaf(w[6],  b.z, s); s = fmaf(w[7],  b.w, s);
    s = fmaf(w[8],  c.x, s); s = fmaf(w[9],  c.y, s); s = fmaf(w[10], c.z, s); s = fmaf(w[11], c.w, s);
    s = fmaf(w[12], d.x, s); s = fmaf(w[13], d.y, s); s = fmaf(w[14], d.z, s); s = fmaf(w[15], d.w, s);
    return s;
}

// ================= K0: xp = x @ Wih1^T + bih1 -> out cols 0:95 (gate 95 dropped)
// 64 rows x 96 cols per block; thread tile 4x6 interleaved (row=rq+16r, col=cq+16c).
__global__ void __launch_bounds__(256) k0_xproj(
    const float* __restrict__ x, const float* __restrict__ Wih1,
    const float* __restrict__ bih1, float* __restrict__ out)
{
    __shared__ float xs[64 * 100];   // stride 100 words: rq*100 %32 = {0,4,8,12} -> conflict-free
    __shared__ float ws[96 * 100];   // cq*100 %32 = cq*4 -> 2-way max (free)
    const int tid = threadIdx.x;
    const size_t row0 = (size_t)blockIdx.x * 64;

    const float* xg = x + row0 * VV;
    for (int i = tid; i < 64 * VV; i += 256) {
        const int r = i / VV, c = i - r * VV;
        xs[r * 100 + c] = xg[i];
    }
    for (int i = tid; i < 96 * VV; i += 256) {
        const int g = i / VV, c = i - g * VV;
        ws[g * 100 + c] = Wih1[i];
    }
    for (int i = tid; i < 64 * 5; i += 256) xs[(i / 5) * 100 + 95 + (i % 5)] = 0.f;
    for (int i = tid; i < 96 * 5; i += 256) ws[(i / 5) * 100 + 95 + (i % 5)] = 0.f;

    const int cq = tid & 15, rq = tid >> 4;
    float acc[4][6];
    #pragma unroll
    for (int c = 0; c < 6; ++c) {
        const float bv = bih1[cq + 16 * c];
        acc[0][c] = bv; acc[1][c] = bv; acc[2][c] = bv; acc[3][c] = bv;
    }
    __syncthreads();

    const float* xp0 = xs + rq * 100;
    const float* wp0 = ws + cq * 100;
    #pragma unroll 4
    for (int k4 = 0; k4 < 24; ++k4) {
        const int k = k4 * 4;
        float4 xv0 = *(const float4*)(xp0 + k);
        float4 xv1 = *(const float4*)(xp0 + 1600 + k);
        float4 xv2 = *(const float4*)(xp0 + 3200 + k);
        float4 xv3 = *(const float4*)(xp0 + 4800 + k);
        #pragma unroll
        for (int c = 0; c < 6; ++c) {
            const float4 wv = *(const float4*)(wp0 + c * 1600 + k);
            acc[0][c] = fmaf(xv0.x, wv.x, acc[0][c]); acc[0][c] = fmaf(xv0.y, wv.y, acc[0][c]);
            acc[0][c] = fmaf(xv0.z, wv.z, acc[0][c]); acc[0][c] = fmaf(xv0.w, wv.w, acc[0][c]);
            acc[1][c] = fmaf(xv1.x, wv.x, acc[1][c]); acc[1][c] = fmaf(xv1.y, wv.y, acc[1][c]);
            acc[1][c] = fmaf(xv1.z, wv.z, acc[1][c]); acc[1][c] = fmaf(xv1.w, wv.w, acc[1][c]);
            acc[2][c] = fmaf(xv2.x, wv.x, acc[2][c]); acc[2][c] = fmaf(xv2.y, wv.y, acc[2][c]);
            acc[2][c] = fmaf(xv2.z, wv.z, acc[2][c]); acc[2][c] = fmaf(xv2.w, wv.w, acc[2][c]);
            acc[3][c] = fmaf(xv3.x, wv.x, acc[3][c]); acc[3][c] = fmaf(xv3.y, wv.y, acc[3][c]);
            acc[3][c] = fmaf(xv3.z, wv.z, acc[3][c]); acc[3][c] = fmaf(xv3.w, wv.w, acc[3][c]);
        }
    }
    #pragma unroll
    for (int r = 0; r < 4; ++r) {
        float* orow = out + (row0 + rq + 16 * r) * VV;
        #pragma unroll
        for (int c = 0; c < 6; ++c) {
            const int g = cq + 16 * c;
            if (g < VV) orow[g] = acc[r][c];
        }
    }
}

// ================= Fused recurrent: 1 block = 1 sequence, 4 waves = pipeline stages
// wave0: L1 (t=g)   reads xp from out, h via LDS
// wave1: L2 (t=g-1) LDS->LDS
// wave2: L3 (t=g-2) LDS->LDS
// wave3: FC (t=g-3) writes out row; also computes xn31(g+1) butterfly
extern "C" __global__ void __launch_bounds__(256) gru_fused(
    const float* __restrict__ x,
    const float* __restrict__ Wih1, const float* __restrict__ Whh1,
    const float* __restrict__ bih1, const float* __restrict__ bhh1,
    const float* __restrict__ Wih2, const float* __restrict__ Whh2,
    const float* __restrict__ bih2, const float* __restrict__ bhh2,
    const float* __restrict__ Wih3, const float* __restrict__ Whh3,
    const float* __restrict__ bih3, const float* __restrict__ bhh3,
    const float* __restrict__ Wfc,  const float* __restrict__ bfc,
    float* __restrict__ out)
{
    __shared__ __align__(16) float hbuf[3][2][32];   // layer, parity(t&1), unit
    __shared__ float xn31[2];

    float (*h1b)[32] = hbuf[0];
    float (*h2b)[32] = hbuf[1];
    float (*h3b)[32] = hbuf[2];

    const int tid = threadIdx.x;
    const int w = tid >> 6, l = tid & 63, j = l & 31, p = l >> 5;

    const size_t b = blockIdx.x;
    const float* xrow = x + b * (size_t)(TT * VV);
    float* orow = out + b * (size_t)(TT * VV);

    if (tid < 192) (&hbuf[0][0][0])[tid] = 0.f;

    // ---- per-stage register weights (p-split: 16 of 32 k per lane) ----
    float wr_[16], wz_[16], wn_[16], ur_[16], uz_[16], un_[16];
    float br = 0.f, bz = 0.f, bni = 0.f, bnh = 0.f;
    float wa = 0.f, wb = 0.f, bn95 = 0.f;
    const int i0 = 2 * l, i1 = 2 * l + 1;

    if (w == 0) {
        #pragma unroll
        for (int c = 0; c < 16; ++c) {
            ur_[c] = Whh1[j * 32 + 16 * p + c];
            uz_[c] = Whh1[(32 + j) * 32 + 16 * p + c];
            un_[c] = Whh1[(64 + j) * 32 + 16 * p + c];
        }
        br = bhh1[j]; bz = bhh1[32 + j]; bnh = bhh1[64 + j];
    } else if (w == 3) {
        #pragma unroll
        for (int c = 0; c < 16; ++c) {
            wr_[c] = Wfc[j * 32 + 16 * p + c];
            wz_[c] = Wfc[(32 + j) * 32 + 16 * p + c];
            wn_[c] = (j < 31) ? Wfc[(64 + j) * 32 + 16 * p + c] : 0.f;
        }
        br = bfc[j]; bz = bfc[32 + j]; bni = (j < 31) ? bfc[64 + j] : 0.f;
        wa = (i0 < VV) ? Wih1[95 * VV + i0] : 0.f;
        wb = (i1 < VV) ? Wih1[95 * VV + i1] : 0.f;
        bn95 = bih1[95];
    } else {
        const float* Wih_ = (w == 1) ? Wih2 : Wih3;
        const float* Whh_ = (w == 1) ? Whh2 : Whh3;
        const float* bih_ = (w == 1) ? bih2 : bih3;
        const float* bhh_ = (w == 1) ? bhh2 : bhh3;
        #pragma unroll
        for (int c = 0; c < 16; ++c) {
            wr_[c] = Wih_[j * 32 + 16 * p + c];
            wz_[c] = Wih_[(32 + j) * 32 + 16 * p + c];
            wn_[c] = Wih_[(64 + j) * 32 + 16 * p + c];
            ur_[c] = Whh_[j * 32 + 16 * p + c];
            uz_[c] = Whh_[(32 + j) * 32 + 16 * p + c];
            un_[c] = Whh_[(64 + j) * 32 + 16 * p + c];
        }
        br = bih_[j] + bhh_[j];
        bz = bih_[32 + j] + bhh_[32 + j];
        bni = bih_[64 + j]; bnh = bhh_[64 + j];
    }

    float (*inB)[32]  = (w == 1) ? h1b : h2b;   // stage input buffer (w=1,2)
    float (*ownB)[32] = (w == 1) ? h2b : h3b;   // stage own-state buffer (w=1,2)

    // ---- prefetch banks ----
    float AxR = 0.f, AxZ = 0.f, AxN = 0.f, BxR = 0.f, BxZ = 0.f, BxN = 0.f; // W0: xp rows
    float xaA = 0.f, xbA = 0.f, xaB = 0.f, xbB = 0.f;                       // W3: x rows
    float hj = 0.f;

    if (w == 0 && p == 0) {
        AxR = orow[j]; AxZ = orow[32 + j]; AxN = (j < 31) ? orow[64 + j] : 0.f;
        const float* r1 = orow + VV;
        BxR = r1[j]; BxZ = r1[32 + j]; BxN = (j < 31) ? r1[64 + j] : 0.f;
    }
    if (w == 3) {
        // xn31(0) prologue butterfly over x(0)
        float a0v = (i0 < VV) ? xrow[i0] : 0.f;
        float b0v = (i1 < VV) ? xrow[i1] : 0.f;
        float v0 = fmaf(wa, a0v, wb * b0v);
        v0 += __shfl_xor(v0, 1);  v0 += __shfl_xor(v0, 2);  v0 += __shfl_xor(v0, 4);
        v0 += __shfl_xor(v0, 8);  v0 += __shfl_xor(v0, 16); v0 += __shfl_xor(v0, 32);
        if (l == 0) xn31[0] = v0 + bn95;
        // banks: B <- x(1) (odd t), A <- x(2) (even t)
        const float* x1 = xrow + 1 * VV;
        const float* x2 = xrow + 2 * VV;
        xaB = (i0 < VV) ? x1[i0] : 0.f; xbB = (i1 < VV) ? x1[i1] : 0.f;
        xaA = (i0 < VV) ? x2[i0] : 0.f; xbA = (i1 < VV) ? x2[i1] : 0.f;
    }
    __syncthreads();

    for (int g = 0; g < TT + 3; ++g) {
        const int par = g & 1, prv = par ^ 1;
        if (w == 0) {
            if (g < TT) {
                const float xr = (par == 0) ? AxR : BxR;
                const float xz = (par == 0) ? AxZ : BxZ;
                const float xn = (par == 0) ? AxN : BxN;
                const float4* hv = (const float4*)(&h1b[prv][16 * p]);
                const float4 h0 = hv[0], h1v = hv[1], h2v = hv[2], h3v = hv[3];
                float hr = dot16(ur_, h0, h1v, h2v, h3v);
                float hz = dot16(uz_, h0, h1v, h2v, h3v);
                float hn = dot16(un_, h0, h1v, h2v, h3v);
                hr += __shfl_xor(hr, 32);
                hz += __shfl_xor(hz, 32);
                hn += __shfl_xor(hn, 32);
                const float xnf = (j == 31) ? xn31[par] : xn;
                const float r = fast_sigmoid(xr + hr + br);
                const float z = fast_sigmoid(xz + hz + bz);
                const float n = fast_tanh(xnf + r * (hn + bnh));
                hj = (1.0f - z) * n + z * hj;
                if (p == 0) {
                    h1b[par][j] = hj;
                    if (g + 2 < TT) {   // refill same-parity bank with xp(g+2)
                        const float* nx = orow + (g + 2) * VV;
                        const float nr = nx[j], nz = nx[32 + j];
                        const float nn = (j < 31) ? nx[64 + j] : 0.f;
                        if (par == 0) { AxR = nr; AxZ = nz; AxN = nn; }
                        else          { BxR = nr; BxZ = nz; BxN = nn; }
                    }
                }
            }
        } else if (w == 3) {
            if (g >= 3) {
                const int t3 = g - 3;
                const float4* gv = (const float4*)(&h3b[t3 & 1][16 * p]);
                const float4 g0 = gv[0], g1 = gv[1], g2 = gv[2], g3 = gv[3];
                float o0 = dot16(wr_, g0, g1, g2, g3);
                float o1 = dot16(wz_, g0, g1, g2, g3);
                float o2 = dot16(wn_, g0, g1, g2, g3);
                o0 += __shfl_xor(o0, 32);
                o1 += __shfl_xor(o1, 32);
                o2 += __shfl_xor(o2, 32);
                if (p == 0) {
                    float* op = orow + t3 * VV;
                    op[j] = o0 + br;
                    op[32 + j] = o1 + bz;
                    if (j < 31) op[64 + j] = o2 + bni;
                }
            }
            if (g + 1 < TT) {   // produce xn31(g+1) into slot (g+1)&1
                const float xa = (prv == 0) ? xaA : xaB;
                const float xb = (prv == 0) ? xbA : xbB;
                float v = fmaf(wa, xa, wb * xb);
                v += __shfl_xor(v, 1);  v += __shfl_xor(v, 2);  v += __shfl_xor(v, 4);
                v += __shfl_xor(v, 8);  v += __shfl_xor(v, 16); v += __shfl_xor(v, 32);
                if (l == 0) xn31[prv] = v + bn95;
                if (g + 3 < TT) {
                    const float* xx = xrow + (g + 3) * VV;
                    const float na = (i0 < VV) ? xx[i0] : 0.f;
                    const float nb = (i1 < VV) ? xx[i1] : 0.f;
                    if (prv == 0) { xaA = na; xbA = nb; }
                    else          { xaB = na; xbB = nb; }
                }
            }
        } else {   // w == 1 (L2, t=g-1) or w == 2 (L3, t=g-2)
            if (g >= w && g < TT + w) {
                const int slot = (g - w) & 1;      // parity of this stage's t
                const float4* iv = (const float4*)(&inB[slot][16 * p]);
                const float4 a0 = iv[0], a1 = iv[1], a2 = iv[2], a3 = iv[3];
                const float4* hv = (const float4*)(&ownB[slot ^ 1][16 * p]);
                const float4 h0 = hv[0], h1v = hv[1], h2v = hv[2], h3v = hv[3];
                float ar = dot16(wr_, a0, a1, a2, a3);
                float az = dot16(wz_, a0, a1, a2, a3);
                float an = dot16(wn_, a0, a1, a2, a3);
                float hr = dot16(ur_, h0, h1v, h2v, h3v);
                float hz = dot16(uz_, h0, h1v, h2v, h3v);
                float hn = dot16(un_, h0, h1v, h2v, h3v);
                float s1 = ar + hr; s1 += __shfl_xor(s1, 32);
                float s2 = az + hz; s2 += __shfl_xor(s2, 32);
                an += __shfl_xor(an, 32);
                hn += __shfl_xor(hn, 32);
                const float r = fast_sigmoid(s1 + br);
                const float z = fast_sigmoid(s2 + bz);
                const float n = fast_tanh(an + bni + r * (hn + bnh));
                hj = (1.0f - z) * n + z * hj;
                if (p == 0) ownB[slot][j] = hj;
            }
        }
        block_sync_lds();
    }
}

extern "C" void kernel_launch(void* const* d_in, const int* in_sizes, int n_in,
                              void* d_out, int out_size, void* d_ws, size_t ws_size,
                              hipStream_t stream) {
    const float* x    = (const float*)d_in[0];
    const float* Wih1 = (const float*)d_in[1];
    const float* Whh1 = (const float*)d_in[2];
    const float* bih1 = (const float*)d_in[3];
    const float* bhh1 = (const float*)d_in[4];
    const float* Wih2 = (const float*)d_in[5];
    const float* Whh2 = (const float*)d_in[6];
    const float* bih2 = (const float*)d_in[7];
    const float* bhh2 = (const float*)d_in[8];
    const float* Wih3 = (const float*)d_in[9];
    const float* Whh3 = (const float*)d_in[10];
    const float* bih3 = (const float*)d_in[11];
    const float* bhh3 = (const float*)d_in[12];
    const float* Wfc  = (const float*)d_in[13];
    const float* bfc  = (const float*)d_in[14];
    float* out = (float*)d_out;

    hipLaunchKernelGGL(k0_xproj, dim3(8192), dim3(256), 0, stream, x, Wih1, bih1, out);
    hipLaunchKernelGGL(gru_fused, dim3(2048), dim3(256), 0, stream,
                       x, Wih1, Whh1, bih1, bhh1,
                       Wih2, Whh2, bih2, bhh2,
                       Wih3, Whh3, bih3, bhh3,
                       Wfc, bfc, out);
}

// Round 5
// 1366.513 us; speedup vs baseline: 1.0958x; 1.0958x over previous
//
#include <hip/hip_runtime.h>

#define TT 256
#define VV 95

__device__ __forceinline__ float fast_sigmoid(float v) {
    return __builtin_amdgcn_rcpf(1.0f + __expf(-v));
}
__device__ __forceinline__ float fast_tanh(float v) {
    return 1.0f - 2.0f * __builtin_amdgcn_rcpf(__expf(2.0f * v) + 1.0f);
}
// Intra-wave LDS ordering only: drain lgkmcnt, no vmcnt drain, no s_barrier.
__device__ __forceinline__ void wave_fence() {
    asm volatile("s_waitcnt lgkmcnt(0)" ::: "memory");
    __builtin_amdgcn_wave_barrier();
}

// ================= K0: xp = x @ Wih1^T + bih1 -> out cols 0:95 (gate 95 dropped)
__global__ void __launch_bounds__(256) k0_xproj(
    const float* __restrict__ x, const float* __restrict__ Wih1,
    const float* __restrict__ bih1, float* __restrict__ out)
{
    __shared__ float xs[64 * 100];
    __shared__ float ws[96 * 100];
    const int tid = threadIdx.x;
    const size_t row0 = (size_t)blockIdx.x * 64;

    const float* xg = x + row0 * VV;
    for (int i = tid; i < 64 * VV; i += 256) {
        const int r = i / VV, c = i - r * VV;
        xs[r * 100 + c] = xg[i];
    }
    for (int i = tid; i < 96 * VV; i += 256) {
        const int g = i / VV, c = i - g * VV;
        ws[g * 100 + c] = Wih1[i];
    }
    for (int i = tid; i < 64 * 5; i += 256) xs[(i / 5) * 100 + 95 + (i % 5)] = 0.f;
    for (int i = tid; i < 96 * 5; i += 256) ws[(i / 5) * 100 + 95 + (i % 5)] = 0.f;

    const int cq = tid & 15, rq = tid >> 4;
    float acc[4][6];
    #pragma unroll
    for (int c = 0; c < 6; ++c) {
        const float bv = bih1[cq + 16 * c];
        acc[0][c] = bv; acc[1][c] = bv; acc[2][c] = bv; acc[3][c] = bv;
    }
    __syncthreads();

    const float* xp0 = xs + rq * 100;
    const float* wp0 = ws + cq * 100;
    #pragma unroll 4
    for (int k4 = 0; k4 < 24; ++k4) {
        const int k = k4 * 4;
        float4 xv0 = *(const float4*)(xp0 + k);
        float4 xv1 = *(const float4*)(xp0 + 1600 + k);
        float4 xv2 = *(const float4*)(xp0 + 3200 + k);
        float4 xv3 = *(const float4*)(xp0 + 4800 + k);
        #pragma unroll
        for (int c = 0; c < 6; ++c) {
            const float4 wv = *(const float4*)(wp0 + c * 1600 + k);
            acc[0][c] = fmaf(xv0.x, wv.x, acc[0][c]); acc[0][c] = fmaf(xv0.y, wv.y, acc[0][c]);
            acc[0][c] = fmaf(xv0.z, wv.z, acc[0][c]); acc[0][c] = fmaf(xv0.w, wv.w, acc[0][c]);
            acc[1][c] = fmaf(xv1.x, wv.x, acc[1][c]); acc[1][c] = fmaf(xv1.y, wv.y, acc[1][c]);
            acc[1][c] = fmaf(xv1.z, wv.z, acc[1][c]); acc[1][c] = fmaf(xv1.w, wv.w, acc[1][c]);
            acc[2][c] = fmaf(xv2.x, wv.x, acc[2][c]); acc[2][c] = fmaf(xv2.y, wv.y, acc[2][c]);
            acc[2][c] = fmaf(xv2.z, wv.z, acc[2][c]); acc[2][c] = fmaf(xv2.w, wv.w, acc[2][c]);
            acc[3][c] = fmaf(xv3.x, wv.x, acc[3][c]); acc[3][c] = fmaf(xv3.y, wv.y, acc[3][c]);
            acc[3][c] = fmaf(xv3.z, wv.z, acc[3][c]); acc[3][c] = fmaf(xv3.w, wv.w, acc[3][c]);
        }
    }
    #pragma unroll
    for (int r = 0; r < 4; ++r) {
        float* orow = out + (row0 + rq + 16 * r) * VV;
        #pragma unroll
        for (int c = 0; c < 6; ++c) {
            const int g = cq + 16 * c;
            if (g < VV) orow[g] = acc[r][c];
        }
    }
}

// ================= K1: L1 recurrence. 2 seqs per wave (half-wave each), full-k dots.
// Reads xp from out cols (prefetched), writes h1 -> out cols 0:32.
extern "C" __global__ void __launch_bounds__(256) k1_l1(
    const float* __restrict__ x, const float* __restrict__ Wih1,
    const float* __restrict__ Whh1, const float* __restrict__ bih1,
    const float* __restrict__ bhh1, float* __restrict__ out)
{
    __shared__ __align__(16) float hb[4][2][32];   // wave, seq-half, unit
    const int tid = threadIdx.x;
    const int w = tid >> 6, l = tid & 63, sh = l >> 5, j = l & 31;

    float ur[32], uz[32], un[32];
    #pragma unroll
    for (int k = 0; k < 32; ++k) {
        ur[k] = Whh1[j * 32 + k];
        uz[k] = Whh1[(32 + j) * 32 + k];
        un[k] = Whh1[(64 + j) * 32 + k];
    }
    const float bhr = bhh1[j], bhz = bhh1[32 + j], bhn = bhh1[64 + j];
    const float w950 = Wih1[95 * VV + j];
    const float w951 = Wih1[95 * VV + 32 + j];
    const float w952 = (j < 31) ? Wih1[95 * VV + 64 + j] : 0.f;
    const float bn95 = bih1[95];

    const size_t b = (size_t)blockIdx.x * 8 + w * 2 + sh;
    const float* xrow = x + b * (size_t)(TT * VV);
    float* orow = out + b * (size_t)(TT * VV);

    hb[w][sh][j] = 0.f;
    float hj = 0.f;

    // prefetch banks A(even t), B(odd t): xp triple + x triple for xn31
    float Ar = orow[j], Az = orow[32 + j], An = (j < 31) ? orow[64 + j] : 0.f;
    float Aa = xrow[j], Ab = xrow[32 + j], Ac = (j < 31) ? xrow[64 + j] : 0.f;
    float Br, Bz, Bn, Ba, Bb, Bc;
    {
        const float* o1 = orow + VV; const float* x1 = xrow + VV;
        Br = o1[j]; Bz = o1[32 + j]; Bn = (j < 31) ? o1[64 + j] : 0.f;
        Ba = x1[j]; Bb = x1[32 + j]; Bc = (j < 31) ? x1[64 + j] : 0.f;
    }
    wave_fence();

    for (int t = 0; t < TT; ++t) {
        const int par = t & 1;
        const float xr  = par ? Br : Ar;
        const float xz  = par ? Bz : Az;
        const float xnv = par ? Bn : An;
        const float xa  = par ? Ba : Aa;
        const float xb  = par ? Bb : Ab;
        const float xc  = par ? Bc : Ac;

        // xn31 (dropped 96th gate): 95-term dot distributed over this seq's 32 lanes
        float v = fmaf(w950, xa, fmaf(w951, xb, w952 * xc));
        v += __shfl_xor(v, 1);  v += __shfl_xor(v, 2);  v += __shfl_xor(v, 4);
        v += __shfl_xor(v, 8);  v += __shfl_xor(v, 16);
        const float xnf = (j == 31) ? (v + bn95) : xnv;

        // full-k h-dots from LDS (broadcast reads, 2 addrs/instr)
        float hr = bhr, hz = bhz, hn = bhn;
        const float4* hv = (const float4*)(&hb[w][sh][0]);
        #pragma unroll
        for (int c = 0; c < 8; ++c) {
            const float4 h4 = hv[c];
            hr = fmaf(ur[4*c], h4.x, hr); hr = fmaf(ur[4*c+1], h4.y, hr);
            hr = fmaf(ur[4*c+2], h4.z, hr); hr = fmaf(ur[4*c+3], h4.w, hr);
            hz = fmaf(uz[4*c], h4.x, hz); hz = fmaf(uz[4*c+1], h4.y, hz);
            hz = fmaf(uz[4*c+2], h4.z, hz); hz = fmaf(uz[4*c+3], h4.w, hz);
            hn = fmaf(un[4*c], h4.x, hn); hn = fmaf(un[4*c+1], h4.y, hn);
            hn = fmaf(un[4*c+2], h4.z, hn); hn = fmaf(un[4*c+3], h4.w, hn);
        }
        const float r = fast_sigmoid(xr + hr);
        const float z = fast_sigmoid(xz + hz);
        const float n = fast_tanh(xnf + r * hn);
        hj = (1.0f - z) * n + z * hj;

        asm volatile("" ::: "memory");
        hb[w][sh][j] = hj;
        orow[t * VV + j] = hj;

        if (t + 2 < TT) {   // refill the bank just consumed with t+2
            const float* nx = orow + (t + 2) * VV;
            const float* xx = xrow + (t + 2) * VV;
            const float nr = nx[j], nz = nx[32 + j], nn = (j < 31) ? nx[64 + j] : 0.f;
            const float na = xx[j], nb = xx[32 + j], nc = (j < 31) ? xx[64 + j] : 0.f;
            if (par == 0) { Ar = nr; Az = nz; An = nn; Aa = na; Ab = nb; Ac = nc; }
            else          { Br = nr; Bz = nz; Bn = nn; Ba = na; Bb = nb; Bc = nc; }
        }
        wave_fence();
    }
}

// ================= K23: L2 and L3 pipelined in one wave (half-wave roles).
// half 0: L2 at t=g (input h1 from out cols 0:32 via LDS ring)
// half 1: L3 at t=g-1 (input h2 from hb2, one step behind)
// h2 never leaves LDS. h3 -> out cols 32:64.
extern "C" __global__ void __launch_bounds__(256, 2) k23_l2l3(
    const float* __restrict__ Wih2, const float* __restrict__ Whh2,
    const float* __restrict__ bih2, const float* __restrict__ bhh2,
    const float* __restrict__ Wih3, const float* __restrict__ Whh3,
    const float* __restrict__ bih3, const float* __restrict__ bhh3,
    float* __restrict__ out)
{
    __shared__ __align__(16) float ist[4][4][32];  // wave, ring(4), unit : h1 staging
    __shared__ __align__(16) float hb2[4][2][32];  // wave, parity, unit
    __shared__ __align__(16) float hb3[4][2][32];

    const int tid = threadIdx.x;
    const int w = tid >> 6, l = tid & 63, sh = l >> 5, j = l & 31;

    const float* Wih_ = sh ? Wih3 : Wih2;
    const float* Whh_ = sh ? Whh3 : Whh2;
    const float* bih_ = sh ? bih3 : bih2;
    const float* bhh_ = sh ? bhh3 : bhh2;

    float vr[32], vz[32], vn[32], ur[32], uz[32], un[32];   // 192 VGPR
    #pragma unroll
    for (int k = 0; k < 32; ++k) {
        vr[k] = Wih_[j * 32 + k];
        vz[k] = Wih_[(32 + j) * 32 + k];
        vn[k] = Wih_[(64 + j) * 32 + k];
        ur[k] = Whh_[j * 32 + k];
        uz[k] = Whh_[(32 + j) * 32 + k];
        un[k] = Whh_[(64 + j) * 32 + k];
    }
    const float br  = bih_[j] + bhh_[j];
    const float bz  = bih_[32 + j] + bhh_[32 + j];
    const float bni = bih_[64 + j], bnh = bhh_[64 + j];

    const size_t b = (size_t)blockIdx.x * 4 + w;
    float* orow = out + b * (size_t)(TT * VV);

    hb2[w][sh][j] = 0.f;    // sh covers both parity slots
    hb3[w][sh][j] = 0.f;
    if (sh == 0) ist[w][0][j] = orow[j];   // h1(0)
    float pn = orow[VV + j];               // h1(1), written to ist at g=0
    float hj = 0.f;
    wave_fence();

    for (int g = 0; g <= TT; ++g) {
        const int tm = g - sh;
        const bool valid = (tm >= 0) && (tm < TT);

        // per-lane LDS bases (half0 own == half1 input == hb2[(g+1)&1] -> broadcast)
        const float* inP  = sh ? &hb2[w][(g + 1) & 1][0] : &ist[w][g & 3][0];
        const float* ownP = sh ? &hb3[w][g & 1][0]       : &hb2[w][(g + 1) & 1][0];

        float ld = 0.f;
        if (g + 2 < TT) ld = orow[(g + 2) * VV + j];   // h1(g+2) prefetch

        float ar = br, az = bz, an = 0.f, hr = 0.f, hz = 0.f, hn = 0.f;
        const float4* iv = (const float4*)inP;
        const float4* hv = (const float4*)ownP;
        #pragma unroll
        for (int c = 0; c < 8; ++c) {
            const float4 a4 = iv[c];
            const float4 h4 = hv[c];
            ar = fmaf(vr[4*c], a4.x, ar); ar = fmaf(vr[4*c+1], a4.y, ar);
            ar = fmaf(vr[4*c+2], a4.z, ar); ar = fmaf(vr[4*c+3], a4.w, ar);
            az = fmaf(vz[4*c], a4.x, az); az = fmaf(vz[4*c+1], a4.y, az);
            az = fmaf(vz[4*c+2], a4.z, az); az = fmaf(vz[4*c+3], a4.w, az);
            an = fmaf(vn[4*c], a4.x, an); an = fmaf(vn[4*c+1], a4.y, an);
            an = fmaf(vn[4*c+2], a4.z, an); an = fmaf(vn[4*c+3], a4.w, an);
            hr = fmaf(ur[4*c], h4.x, hr); hr = fmaf(ur[4*c+1], h4.y, hr);
            hr = fmaf(ur[4*c+2], h4.z, hr); hr = fmaf(ur[4*c+3], h4.w, hr);
            hz = fmaf(uz[4*c], h4.x, hz); hz = fmaf(uz[4*c+1], h4.y, hz);
            hz = fmaf(uz[4*c+2], h4.z, hz); hz = fmaf(uz[4*c+3], h4.w, hz);
            hn = fmaf(un[4*c], h4.x, hn); hn = fmaf(un[4*c+1], h4.y, hn);
            hn = fmaf(un[4*c+2], h4.z, hn); hn = fmaf(un[4*c+3], h4.w, hn);
        }
        const float r = fast_sigmoid(ar + hr);
        const float z = fast_sigmoid(az + hz);
        const float n = fast_tanh(an + bni + r * (hn + bnh));
        const float hnew = (1.0f - z) * n + z * hj;

        asm volatile("" ::: "memory");
        if (valid) {
            hj = hnew;
            float* wp = sh ? &hb3[w][(g + 1) & 1][j] : &hb2[w][g & 1][j];
            *wp = hj;
            if (sh) orow[tm * VV + 32 + j] = hj;
        }
        if (sh == 0 && g + 1 < TT) ist[w][(g + 1) & 3][j] = pn;
        pn = ld;
        wave_fence();
    }
}

// ================= K4: FC GEMM. out[row, 0:95] = h3(row) @ Wfc^T + bfc (in-place per row)
__global__ void __launch_bounds__(256) k4_fc(
    const float* __restrict__ Wfc, const float* __restrict__ bfc,
    float* __restrict__ out)
{
    __shared__ float hs[64 * 36];
    __shared__ float ws[96 * 36];
    const int tid = threadIdx.x;
    const size_t row0 = (size_t)blockIdx.x * 64;

    for (int i = tid; i < 64 * 32; i += 256) {
        const int r = i >> 5, k = i & 31;
        hs[r * 36 + k] = out[(row0 + r) * VV + 32 + k];
    }
    for (int i = tid; i < 95 * 32; i += 256) {
        const int g = i >> 5, k = i & 31;
        ws[g * 36 + k] = Wfc[i];
    }
    for (int i = tid; i < 32; i += 256) ws[95 * 36 + i] = 0.f;   // pad row 95
    const int cq = tid & 15, rq = tid >> 4;
    float acc[4][6];
    #pragma unroll
    for (int c = 0; c < 6; ++c) {
        const int g = cq + 16 * c;
        const float bv = (g < VV) ? bfc[g] : 0.f;
        acc[0][c] = bv; acc[1][c] = bv; acc[2][c] = bv; acc[3][c] = bv;
    }
    __syncthreads();

    #pragma unroll
    for (int k4 = 0; k4 < 8; ++k4) {
        const int k = k4 * 4;
        const float4 h0 = *(const float4*)(hs + (rq     ) * 36 + k);
        const float4 h1 = *(const float4*)(hs + (rq + 16) * 36 + k);
        const float4 h2 = *(const float4*)(hs + (rq + 32) * 36 + k);
        const float4 h3 = *(const float4*)(hs + (rq + 48) * 36 + k);
        #pragma unroll
        for (int c = 0; c < 6; ++c) {
            const float4 wv = *(const float4*)(ws + (cq + 16 * c) * 36 + k);
            acc[0][c] = fmaf(h0.x, wv.x, acc[0][c]); acc[0][c] = fmaf(h0.y, wv.y, acc[0][c]);
            acc[0][c] = fmaf(h0.z, wv.z, acc[0][c]); acc[0][c] = fmaf(h0.w, wv.w, acc[0][c]);
            acc[1][c] = fmaf(h1.x, wv.x, acc[1][c]); acc[1][c] = fmaf(h1.y, wv.y, acc[1][c]);
            acc[1][c] = fmaf(h1.z, wv.z, acc[1][c]); acc[1][c] = fmaf(h1.w, wv.w, acc[1][c]);
            acc[2][c] = fmaf(h2.x, wv.x, acc[2][c]); acc[2][c] = fmaf(h2.y, wv.y, acc[2][c]);
            acc[2][c] = fmaf(h2.z, wv.z, acc[2][c]); acc[2][c] = fmaf(h2.w, wv.w, acc[2][c]);
            acc[3][c] = fmaf(h3.x, wv.x, acc[3][c]); acc[3][c] = fmaf(h3.y, wv.y, acc[3][c]);
            acc[3][c] = fmaf(h3.z, wv.z, acc[3][c]); acc[3][c] = fmaf(h3.w, wv.w, acc[3][c]);
        }
    }
    #pragma unroll
    for (int r = 0; r < 4; ++r) {
        float* orow = out + (row0 + rq + 16 * r) * VV;
        #pragma unroll
        for (int c = 0; c < 6; ++c) {
            const int g = cq + 16 * c;
            if (g < VV) orow[g] = acc[r][c];
        }
    }
}

extern "C" void kernel_launch(void* const* d_in, const int* in_sizes, int n_in,
                              void* d_out, int out_size, void* d_ws, size_t ws_size,
                              hipStream_t stream) {
    const float* x    = (const float*)d_in[0];
    const float* Wih1 = (const float*)d_in[1];
    const float* Whh1 = (const float*)d_in[2];
    const float* bih1 = (const float*)d_in[3];
    const float* bhh1 = (const float*)d_in[4];
    const float* Wih2 = (const float*)d_in[5];
    const float* Whh2 = (const float*)d_in[6];
    const float* bih2 = (const float*)d_in[7];
    const float* bhh2 = (const float*)d_in[8];
    const float* Wih3 = (const float*)d_in[9];
    const float* Whh3 = (const float*)d_in[10];
    const float* bih3 = (const float*)d_in[11];
    const float* bhh3 = (const float*)d_in[12];
    const float* Wfc  = (const float*)d_in[13];
    const float* bfc  = (const float*)d_in[14];
    float* out = (float*)d_out;

    hipLaunchKernelGGL(k0_xproj, dim3(8192), dim3(256), 0, stream, x, Wih1, bih1, out);
    hipLaunchKernelGGL(k1_l1,    dim3(256),  dim3(256), 0, stream, x, Wih1, Whh1, bih1, bhh1, out);
    hipLaunchKernelGGL(k23_l2l3, dim3(512),  dim3(256), 0, stream,
                       Wih2, Whh2, bih2, bhh2, Wih3, Whh3, bih3, bhh3, out);
    hipLaunchKernelGGL(k4_fc,    dim3(8192), dim3(256), 0, stream, Wfc, bfc, out);
}

// Round 6
// 996.812 us; speedup vs baseline: 1.5022x; 1.3709x over previous
//
#include <hip/hip_runtime.h>

#define TT 256
#define VV 95

__device__ __forceinline__ float fast_sigmoid(float v) {
    return __builtin_amdgcn_rcpf(1.0f + __expf(-v));
}
__device__ __forceinline__ float fast_tanh(float v) {
    return 1.0f - 2.0f * __builtin_amdgcn_rcpf(__expf(2.0f * v) + 1.0f);
}
// Intra-wave LDS ordering only: drains lgkmcnt (DS), NOT vmcnt -> staging stays in flight.
__device__ __forceinline__ void wave_fence() {
    asm volatile("s_waitcnt lgkmcnt(0)" ::: "memory");
    __builtin_amdgcn_wave_barrier();
}
__device__ __forceinline__ void vm_wait0() {
    asm volatile("s_waitcnt vmcnt(0)" ::: "memory");
}
// async global->LDS, 4B per lane, LDS dest = uniform base + lane*4
__device__ __forceinline__ void gld_lds4(const float* g, float* lds) {
    __builtin_amdgcn_global_load_lds(
        (const __attribute__((address_space(1))) void*)g,
        (__attribute__((address_space(3))) void*)lds,
        4, 0, 0);
}
// stage 760 contiguous floats (8 rows x 95)
__device__ __forceinline__ void stage760(const float* g, float* lds, int l) {
    #pragma unroll
    for (int i = 0; i < 11; ++i) gld_lds4(g + i * 64 + l, lds + i * 64);
    if (l < 56) gld_lds4(g + 704 + l, lds + 704);
}
// stage 8 rows x 32 floats (row stride VV in global, 32 in LDS), lanes 0-31 only
__device__ __forceinline__ void stage8x32(const float* g, float* lds, int l) {
    if (l < 32) {
        #pragma unroll
        for (int r = 0; r < 8; ++r) gld_lds4(g + r * VV + l, lds + r * 32);
    }
}

__device__ __forceinline__ float dot16(const float* w, float4 a, float4 b, float4 c, float4 d) {
    float s = 0.0f;
    s = fmaf(w[0],  a.x, s); s = fmaf(w[1],  a.y, s); s = fmaf(w[2],  a.z, s); s = fmaf(w[3],  a.w, s);
    s = fmaf(w[4],  b.x, s); s = fmaf(w[5],  b.y, s); s = fmaf(w[6],  b.z, s); s = fmaf(w[7],  b.w, s);
    s = fmaf(w[8],  c.x, s); s = fmaf(w[9],  c.y, s); s = fmaf(w[10], c.z, s); s = fmaf(w[11], c.w, s);
    s = fmaf(w[12], d.x, s); s = fmaf(w[13], d.y, s); s = fmaf(w[14], d.z, s); s = fmaf(w[15], d.w, s);
    return s;
}

// ================= K0: xp = x @ Wih1^T + bih1 -> out cols 0:95 (gate 95 dropped)
__global__ void __launch_bounds__(256) k0_xproj(
    const float* __restrict__ x, const float* __restrict__ Wih1,
    const float* __restrict__ bih1, float* __restrict__ out)
{
    __shared__ float xs[64 * 100];
    __shared__ float ws[96 * 100];
    const int tid = threadIdx.x;
    const size_t row0 = (size_t)blockIdx.x * 64;

    const float* xg = x + row0 * VV;
    for (int i = tid; i < 64 * VV; i += 256) {
        const int r = i / VV, c = i - r * VV;
        xs[r * 100 + c] = xg[i];
    }
    for (int i = tid; i < 96 * VV; i += 256) {
        const int g = i / VV, c = i - g * VV;
        ws[g * 100 + c] = Wih1[i];
    }
    for (int i = tid; i < 64 * 5; i += 256) xs[(i / 5) * 100 + 95 + (i % 5)] = 0.f;
    for (int i = tid; i < 96 * 5; i += 256) ws[(i / 5) * 100 + 95 + (i % 5)] = 0.f;

    const int cq = tid & 15, rq = tid >> 4;
    float acc[4][6];
    #pragma unroll
    for (int c = 0; c < 6; ++c) {
        const float bv = bih1[cq + 16 * c];
        acc[0][c] = bv; acc[1][c] = bv; acc[2][c] = bv; acc[3][c] = bv;
    }
    __syncthreads();

    const float* xp0 = xs + rq * 100;
    const float* wp0 = ws + cq * 100;
    #pragma unroll 4
    for (int k4 = 0; k4 < 24; ++k4) {
        const int k = k4 * 4;
        float4 xv0 = *(const float4*)(xp0 + k);
        float4 xv1 = *(const float4*)(xp0 + 1600 + k);
        float4 xv2 = *(const float4*)(xp0 + 3200 + k);
        float4 xv3 = *(const float4*)(xp0 + 4800 + k);
        #pragma unroll
        for (int c = 0; c < 6; ++c) {
            const float4 wv = *(const float4*)(wp0 + c * 1600 + k);
            acc[0][c] = fmaf(xv0.x, wv.x, acc[0][c]); acc[0][c] = fmaf(xv0.y, wv.y, acc[0][c]);
            acc[0][c] = fmaf(xv0.z, wv.z, acc[0][c]); acc[0][c] = fmaf(xv0.w, wv.w, acc[0][c]);
            acc[1][c] = fmaf(xv1.x, wv.x, acc[1][c]); acc[1][c] = fmaf(xv1.y, wv.y, acc[1][c]);
            acc[1][c] = fmaf(xv1.z, wv.z, acc[1][c]); acc[1][c] = fmaf(xv1.w, wv.w, acc[1][c]);
            acc[2][c] = fmaf(xv2.x, wv.x, acc[2][c]); acc[2][c] = fmaf(xv2.y, wv.y, acc[2][c]);
            acc[2][c] = fmaf(xv2.z, wv.z, acc[2][c]); acc[2][c] = fmaf(xv2.w, wv.w, acc[2][c]);
            acc[3][c] = fmaf(xv3.x, wv.x, acc[3][c]); acc[3][c] = fmaf(xv3.y, wv.y, acc[3][c]);
            acc[3][c] = fmaf(xv3.z, wv.z, acc[3][c]); acc[3][c] = fmaf(xv3.w, wv.w, acc[3][c]);
        }
    }
    #pragma unroll
    for (int r = 0; r < 4; ++r) {
        float* orow = out + (row0 + rq + 16 * r) * VV;
        #pragma unroll
        for (int c = 0; c < 6; ++c) {
            const int g = cq + 16 * c;
            if (g < VV) orow[g] = acc[r][c];
        }
    }
}

// ================= K1: L1 recurrence. 1 seq/wave, p-split k, chunk-staged xp + x.
extern "C" __global__ void __launch_bounds__(256, 2) k1_l1(
    const float* __restrict__ x, const float* __restrict__ Wih1,
    const float* __restrict__ Whh1, const float* __restrict__ bih1,
    const float* __restrict__ bhh1, float* __restrict__ out)
{
    __shared__ __align__(16) float xpb[4][2][768];   // xp chunks: 8 rows x 95
    __shared__ __align__(16) float xb [4][2][768];   // x  chunks: 8 rows x 95
    __shared__ __align__(16) float hb[4][32];

    const int tid = threadIdx.x;
    const int w = tid >> 6, l = tid & 63, p = l >> 5, j = l & 31;

    float ur[16], uz[16], un[16];
    #pragma unroll
    for (int c = 0; c < 16; ++c) {
        ur[c] = Whh1[j * 32 + 16 * p + c];
        uz[c] = Whh1[(32 + j) * 32 + 16 * p + c];
        un[c] = Whh1[(64 + j) * 32 + 16 * p + c];
    }
    const float bhr = bhh1[j], bhz = bhh1[32 + j], bhn = bhh1[64 + j];
    // dropped 96th gate: row 95 of Wih1, distributed 64+31 over the wave
    const float wa = Wih1[95 * VV + l];
    const float wb = (l < 31) ? Wih1[95 * VV + 64 + l] : 0.f;
    const float bn95 = bih1[95];

    const size_t b = (size_t)blockIdx.x * 4 + w;
    const float* xrow = x + b * (size_t)(TT * VV);
    float* orow = out + b * (size_t)(TT * VV);

    if (p == 0) hb[w][j] = 0.f;
    float hj = 0.f;

    // prologue: stage rows 0..7
    stage760(orow, &xpb[w][0][0], l);
    stage760(xrow, &xb[w][0][0], l);
    wave_fence();

    for (int t = 0; t < TT; ++t) {
        const int tc = t & 7;
        const int cb = (t >> 3) & 1;
        if (tc == 0) {
            vm_wait0();                     // current chunk resident (issued 8 steps ago)
            if (t + 8 < TT) {
                stage760(orow + (t + 8) * VV, &xpb[w][cb ^ 1][0], l);
                stage760(xrow + (t + 8) * VV, &xb[w][cb ^ 1][0], l);
            }
        }
        const float* xpc = &xpb[w][cb][tc * VV];
        const float* xc  = &xb [w][cb][tc * VV];
        const float xr  = xpc[j];
        const float xz  = xpc[32 + j];
        const float xn  = (j < 31) ? xpc[64 + j] : 0.f;
        const float xav = xc[l];
        const float xbv = (l < 31) ? xc[64 + l] : 0.f;

        // xn31 butterfly (independent chain, overlaps h-dots)
        float v = fmaf(wa, xav, wb * xbv);
        v += __shfl_xor(v, 1);  v += __shfl_xor(v, 2);  v += __shfl_xor(v, 4);
        v += __shfl_xor(v, 8);  v += __shfl_xor(v, 16); v += __shfl_xor(v, 32);

        const float4* hv = (const float4*)(&hb[w][16 * p]);
        const float4 h0 = hv[0], h1v = hv[1], h2v = hv[2], h3v = hv[3];
        float hr = dot16(ur, h0, h1v, h2v, h3v);
        float hz = dot16(uz, h0, h1v, h2v, h3v);
        float hn = dot16(un, h0, h1v, h2v, h3v);
        hr += __shfl_xor(hr, 32);
        hz += __shfl_xor(hz, 32);
        hn += __shfl_xor(hn, 32);

        const float xnf = (j == 31) ? (v + bn95) : xn;
        const float r = fast_sigmoid(xr + hr + bhr);
        const float z = fast_sigmoid(xz + hz + bhz);
        const float n = fast_tanh(xnf + r * (hn + bhn));
        hj = (1.0f - z) * n + z * hj;

        asm volatile("" ::: "memory");
        if (p == 0) { hb[w][j] = hj; orow[t * VV + j] = hj; }
        wave_fence();
    }
}

// ================= K23: generic 32->32 GRU layer. 1 seq/wave, p-split, chunk-staged input.
// reads h_in from out cols [in_col, in_col+32), writes h_out -> out cols [32, 64)
extern "C" __global__ void __launch_bounds__(256, 2) k23_layer(
    const float* __restrict__ Wih, const float* __restrict__ Whh,
    const float* __restrict__ bih, const float* __restrict__ bhh,
    float* __restrict__ out, int in_col)
{
    __shared__ __align__(16) float ib[4][2][256];   // 8 rows x 32 input floats
    __shared__ __align__(16) float hb[4][32];

    const int tid = threadIdx.x;
    const int w = tid >> 6, l = tid & 63, p = l >> 5, j = l & 31;

    float vr[16], vz[16], vn[16], ur[16], uz[16], un[16];   // 96 VGPR
    #pragma unroll
    for (int c = 0; c < 16; ++c) {
        vr[c] = Wih[j * 32 + 16 * p + c];
        vz[c] = Wih[(32 + j) * 32 + 16 * p + c];
        vn[c] = Wih[(64 + j) * 32 + 16 * p + c];
        ur[c] = Whh[j * 32 + 16 * p + c];
        uz[c] = Whh[(32 + j) * 32 + 16 * p + c];
        un[c] = Whh[(64 + j) * 32 + 16 * p + c];
    }
    const float br  = bih[j] + bhh[j];
    const float bz  = bih[32 + j] + bhh[32 + j];
    const float bni = bih[64 + j], bnh = bhh[64 + j];

    const size_t b = (size_t)blockIdx.x * 4 + w;
    float* orow = out + b * (size_t)(TT * VV);

    if (p == 0) hb[w][j] = 0.f;
    float hj = 0.f;

    stage8x32(orow + in_col, &ib[w][0][0], l);   // rows 0..7
    wave_fence();

    for (int t = 0; t < TT; ++t) {
        const int tc = t & 7;
        const int cb = (t >> 3) & 1;
        if (tc == 0) {
            vm_wait0();
            if (t + 8 < TT)
                stage8x32(orow + (t + 8) * VV + in_col, &ib[w][cb ^ 1][0], l);
        }
        const float4* iv = (const float4*)(&ib[w][cb][tc * 32 + 16 * p]);
        const float4 a0 = iv[0], a1 = iv[1], a2 = iv[2], a3 = iv[3];
        const float4* hv = (const float4*)(&hb[w][16 * p]);
        const float4 h0 = hv[0], h1v = hv[1], h2v = hv[2], h3v = hv[3];

        float ar = dot16(vr, a0, a1, a2, a3);
        float az = dot16(vz, a0, a1, a2, a3);
        float an = dot16(vn, a0, a1, a2, a3);
        float hr = dot16(ur, h0, h1v, h2v, h3v);
        float hz = dot16(uz, h0, h1v, h2v, h3v);
        float hn = dot16(un, h0, h1v, h2v, h3v);

        float s1 = ar + hr; s1 += __shfl_xor(s1, 32);
        float s2 = az + hz; s2 += __shfl_xor(s2, 32);
        an += __shfl_xor(an, 32);
        hn += __shfl_xor(hn, 32);

        const float r = fast_sigmoid(s1 + br);
        const float z = fast_sigmoid(s2 + bz);
        const float n = fast_tanh(an + bni + r * (hn + bnh));
        hj = (1.0f - z) * n + z * hj;

        asm volatile("" ::: "memory");
        if (p == 0) { hb[w][j] = hj; orow[t * VV + 32 + j] = hj; }
        wave_fence();
    }
}

// ================= K4: FC GEMM. out[row, 0:95] = h3(row) @ Wfc^T + bfc (in-place per row)
__global__ void __launch_bounds__(256) k4_fc(
    const float* __restrict__ Wfc, const float* __restrict__ bfc,
    float* __restrict__ out)
{
    __shared__ float hs[64 * 36];
    __shared__ float ws[96 * 36];
    const int tid = threadIdx.x;
    const size_t row0 = (size_t)blockIdx.x * 64;

    for (int i = tid; i < 64 * 32; i += 256) {
        const int r = i >> 5, k = i & 31;
        hs[r * 36 + k] = out[(row0 + r) * VV + 32 + k];
    }
    for (int i = tid; i < 95 * 32; i += 256) {
        const int g = i >> 5, k = i & 31;
        ws[g * 36 + k] = Wfc[i];
    }
    for (int i = tid; i < 32; i += 256) ws[95 * 36 + i] = 0.f;
    const int cq = tid & 15, rq = tid >> 4;
    float acc[4][6];
    #pragma unroll
    for (int c = 0; c < 6; ++c) {
        const int g = cq + 16 * c;
        const float bv = (g < VV) ? bfc[g] : 0.f;
        acc[0][c] = bv; acc[1][c] = bv; acc[2][c] = bv; acc[3][c] = bv;
    }
    __syncthreads();

    #pragma unroll
    for (int k4 = 0; k4 < 8; ++k4) {
        const int k = k4 * 4;
        const float4 h0 = *(const float4*)(hs + (rq     ) * 36 + k);
        const float4 h1 = *(const float4*)(hs + (rq + 16) * 36 + k);
        const float4 h2 = *(const float4*)(hs + (rq + 32) * 36 + k);
        const float4 h3 = *(const float4*)(hs + (rq + 48) * 36 + k);
        #pragma unroll
        for (int c = 0; c < 6; ++c) {
            const float4 wv = *(const float4*)(ws + (cq + 16 * c) * 36 + k);
            acc[0][c] = fmaf(h0.x, wv.x, acc[0][c]); acc[0][c] = fmaf(h0.y, wv.y, acc[0][c]);
            acc[0][c] = fmaf(h0.z, wv.z, acc[0][c]); acc[0][c] = fmaf(h0.w, wv.w, acc[0][c]);
            acc[1][c] = fmaf(h1.x, wv.x, acc[1][c]); acc[1][c] = fmaf(h1.y, wv.y, acc[1][c]);
            acc[1][c] = fmaf(h1.z, wv.z, acc[1][c]); acc[1][c] = fmaf(h1.w, wv.w, acc[1][c]);
            acc[2][c] = fmaf(h2.x, wv.x, acc[2][c]); acc[2][c] = fmaf(h2.y, wv.y, acc[2][c]);
            acc[2][c] = fmaf(h2.z, wv.z, acc[2][c]); acc[2][c] = fmaf(h2.w, wv.w, acc[2][c]);
            acc[3][c] = fmaf(h3.x, wv.x, acc[3][c]); acc[3][c] = fmaf(h3.y, wv.y, acc[3][c]);
            acc[3][c] = fmaf(h3.z, wv.z, acc[3][c]); acc[3][c] = fmaf(h3.w, wv.w, acc[3][c]);
        }
    }
    #pragma unroll
    for (int r = 0; r < 4; ++r) {
        float* orow = out + (row0 + rq + 16 * r) * VV;
        #pragma unroll
        for (int c = 0; c < 6; ++c) {
            const int g = cq + 16 * c;
            if (g < VV) orow[g] = acc[r][c];
        }
    }
}

extern "C" void kernel_launch(void* const* d_in, const int* in_sizes, int n_in,
                              void* d_out, int out_size, void* d_ws, size_t ws_size,
                              hipStream_t stream) {
    const float* x    = (const float*)d_in[0];
    const float* Wih1 = (const float*)d_in[1];
    const float* Whh1 = (const float*)d_in[2];
    const float* bih1 = (const float*)d_in[3];
    const float* bhh1 = (const float*)d_in[4];
    const float* Wih2 = (const float*)d_in[5];
    const float* Whh2 = (const float*)d_in[6];
    const float* bih2 = (const float*)d_in[7];
    const float* bhh2 = (const float*)d_in[8];
    const float* Wih3 = (const float*)d_in[9];
    const float* Whh3 = (const float*)d_in[10];
    const float* bih3 = (const float*)d_in[11];
    const float* bhh3 = (const float*)d_in[12];
    const float* Wfc  = (const float*)d_in[13];
    const float* bfc  = (const float*)d_in[14];
    float* out = (float*)d_out;

    hipLaunchKernelGGL(k0_xproj,  dim3(8192), dim3(256), 0, stream, x, Wih1, bih1, out);
    hipLaunchKernelGGL(k1_l1,     dim3(512),  dim3(256), 0, stream, x, Wih1, Whh1, bih1, bhh1, out);
    hipLaunchKernelGGL(k23_layer, dim3(512),  dim3(256), 0, stream, Wih2, Whh2, bih2, bhh2, out, 0);
    hipLaunchKernelGGL(k23_layer, dim3(512),  dim3(256), 0, stream, Wih3, Whh3, bih3, bhh3, out, 32);
    hipLaunchKernelGGL(k4_fc,     dim3(8192), dim3(256), 0, stream, Wfc, bfc, out);
}